// Round 3
// baseline (730.942 us; speedup 1.0000x reference)
//
#include <hip/hip_runtime.h>
#include <hip/hip_bf16.h>

// PINN fused forward+jvp^2 via split-fp16 MFMA.
// R13: BS=8, 512 thr, 33.3KB LDS, forced 64 VGPR -> 4 blocks/CU, 32 waves/CU
// (2x the wave-level latency hiding of R12). MFMA columns are PACKED:
// B1 = [vhi(8 samples) | vlo(8)], B2 = [dhi | ddh] -- vlo/ddh plane rows
// directly follow vhi/dhi so the B-address formula is unchanged.
// Per (mt,kt) only 3 MFMAs: accV += Ahi*B1; accV += Alo*B1; accD += Ahi*B2.
// accV cols c and c+8 sum (one shfl_xor(8)) to the FULL split product
// (hi*vh+lo*vh+hi*vl+lo*vl -- more accurate than R12). accD halves = d,dd.
// Per-wave A-staging dropped (register budget): TLP from 8 waves/SIMD now
// hides the L2 latency instead. Epilogue: lower half-lanes write vhi/vlo,
// upper half write dhi/ddh.

#define NSAMP 65536
#define Q     100
#define DTC   0.8f
#define BS    8
#define THREADS 512
#define STR   520          // LDS row stride (halves)

typedef _Float16 h8 __attribute__((ext_vector_type(8)));
typedef _Float16 h4 __attribute__((ext_vector_type(4)));
typedef float    f4 __attribute__((ext_vector_type(4)));

// ---- packed fragment-ready weight geometry (halves) ----
// per layer: MT * KT * 512 halves (frag = 64 lanes x 8 halves)
// L1: MT=4,  KT=1  ->   2048
// L2: MT=14, KT=2  ->  14336
// L3: MT=32, KT=7  -> 114688
// L4: MT=14, KT=16 -> 114688
// L5: MT=7,  KT=7  ->  25088
#define SW 270848
#define C1 0
#define C2 2048
#define C3 16384
#define C4 131072
#define C5 245760
#define BP1 0
#define BP2 64
#define BP3 288
#define BP4 800
#define BP5 1024
#define BPTOT 1136
#define WS_BIAS_BYTE_OFF (SW*2*2)

__device__ __forceinline__ float fast_tanh(float z) {
    float az = fabsf(z);
    float e  = __expf(-2.0f * az);
    float r  = __builtin_amdgcn_rcpf(1.0f + e);
    float t  = (1.0f - e) * r;
    return copysignf(t, z);
}

struct Split { _Float16 hi, lo; };
__device__ __forceinline__ Split split16(float v) {
    Split s;
    s.hi = (_Float16)v;
    s.lo = (_Float16)(v - (float)s.hi);
    return s;
}

// ---------------- pre-pass: split/pad/PACK weights + biases into d_ws ----------------
__global__ __launch_bounds__(256) void prepass(
    const float* __restrict__ W1, const float* __restrict__ b1,
    const float* __restrict__ W2, const float* __restrict__ b2,
    const float* __restrict__ W3, const float* __restrict__ b3,
    const float* __restrict__ W4, const float* __restrict__ b4,
    const float* __restrict__ W5, const float* __restrict__ b5,
    _Float16* __restrict__ whi, float* __restrict__ biasP)
{
    int idx = blockIdx.x * 256 + threadIdx.x;
    _Float16* wlo = whi + SW;
    if (idx < SW) {
        int base, KT, K, FOUT; const float* W;
        if      (idx < C2) { base=C1; KT=1;  K=20;  FOUT=50;  W=W1; }
        else if (idx < C3) { base=C2; KT=2;  K=50;  FOUT=200; W=W2; }
        else if (idx < C4) { base=C3; KT=7;  K=200; FOUT=500; W=W3; }
        else if (idx < C5) { base=C4; KT=16; K=500; FOUT=200; W=W4; }
        else               { base=C5; KT=7;  K=200; FOUT=100; W=W5; }
        int r    = idx - base;
        int frag = r >> 9;
        int f    = r & 511;
        int lane = f >> 3;
        int e    = f & 7;
        int colS = lane & 15;
        int kg   = lane >> 4;
        int mt   = frag / KT;
        int kt   = frag - mt * KT;
        int o = mt * 16 + colS;
        int k = kt * 32 + kg * 8 + e;
        float v = (o < FOUT && k < K) ? W[o * K + k] : 0.f;
        Split sp = split16(v);
        whi[idx] = sp.hi; wlo[idx] = sp.lo;
    } else if (idx < SW + BPTOT) {
        int b = idx - SW;
        const float* src; int FOUT; int o;
        if      (b < BP2)  { src=b1; FOUT=50;  o=b;        }
        else if (b < BP3)  { src=b2; FOUT=200; o=b-BP2;    }
        else if (b < BP4)  { src=b3; FOUT=500; o=b-BP3;    }
        else if (b < BP5)  { src=b4; FOUT=200; o=b-BP4;    }
        else               { src=b5; FOUT=100; o=b-BP5;    }
        biasP[b] = (o < FOUT) ? src[o] : 0.f;
    }
}

// ---------------- one MFMA layer (packed columns, 8 samples) ----------------
// LDS: 32 rows x STR halves. Rows 0-7: vhi, 8-15: vlo, 16-23: dhi, 24-31: ddh.
// B1 (v-region) lane l -> row = l&15 (covers vhi|vlo), k0 = (l>>4)*8 + kt*32.
// B2 (d-region) = same formula at smem + 16*STR.
// A-frag: PACKED: base + (mt*KT + kt)*512 + lane*8 -> coalesced 1KB load.
// C/D: col(lane&15): c<8 -> channel A of sample c, c>=8 -> channel B of c-8.
// 3 MFMAs per (mt,kt): accV += Ahi*B1 + Alo*B1 ; accD += Ahi*B2.
template<int KP, int MTILES, int NMT, int NWACT, int FOUT, bool TANH>
__device__ __forceinline__ void layer_mfma(
    const _Float16* __restrict__ whi, const _Float16* __restrict__ wlo,
    int wcoff, const float* __restrict__ biasP,
    _Float16* smem, int lane, int wv)
{
    constexpr int KT = KP / 32;
    static_assert(MTILES == NMT * NWACT, "exact tiling expected");
    const int colS = lane & 15;
    const int kg   = lane >> 4;
    const bool act = (wv < NWACT);
    _Float16* Pv = smem;
    _Float16* Pd = smem + 16 * STR;

    f4 accV[NMT], accD[NMT];

    if (act) {
#pragma unroll
        for (int i = 0; i < NMT; ++i) {
            accV[i] = (f4){0.f, 0.f, 0.f, 0.f};
            accD[i] = (f4){0.f, 0.f, 0.f, 0.f};
        }

        const int boff = colS * STR + kg * 8;

        unsigned woff[NMT];
#pragma unroll
        for (int i = 0; i < NMT; ++i)
            woff[i] = (unsigned)(wcoff + ((wv + NWACT * i) * KT) * 512 + lane * 8);

#pragma unroll 2
        for (int kt = 0; kt < KT; ++kt) {
            const int kb  = kt * 32;
            const int kwb = kt * 512;
            h8 B1 = *(const h8*)(Pv + boff + kb);
            h8 B2 = *(const h8*)(Pd + boff + kb);
            __builtin_amdgcn_s_setprio(1);
#pragma unroll
            for (int i = 0; i < NMT; ++i) {
                h8 Ahi = *(const h8*)(whi + woff[i] + kwb);
                h8 Alo = *(const h8*)(wlo + woff[i] + kwb);
                accV[i] = __builtin_amdgcn_mfma_f32_16x16x32_f16(Ahi, B1, accV[i], 0, 0, 0);
                accV[i] = __builtin_amdgcn_mfma_f32_16x16x32_f16(Alo, B1, accV[i], 0, 0, 0);
                accD[i] = __builtin_amdgcn_mfma_f32_16x16x32_f16(Ahi, B2, accD[i], 0, 0, 0);
            }
            __builtin_amdgcn_s_setprio(0);
        }
    }
    __syncthreads();   // all reads of planes complete before in-place overwrite

    if (act) {
        const bool lowHalf = (colS < 8);
        const int  s       = colS & 7;
#pragma unroll
        for (int i = 0; i < NMT; ++i) {
            int mt = wv + NWACT * i;
            int o0 = mt * 16 + kg * 4;
            f4 bi = *(const f4*)(biasP + o0);
            h4 pA, pB;   // lowHalf: (vhi, vlo) ; else: (dhi, ddh)
#pragma unroll
            for (int r = 0; r < 4; ++r) {
                float a1  = accV[i][r];
                float a2  = accD[i][r];
                float a1s = __shfl_xor(a1, 8);
                float a2s = __shfl_xor(a2, 8);
                float zv  = a1 + a1s + bi[r];        // full split product
                float zd  = lowHalf ? a2  : a2s;
                float zdd = lowHalf ? a2s : a2;
                float ov, od, odd;
                if constexpr (TANH) {
                    float t  = fast_tanh(zv);
                    float s2 = 1.0f - t * t;
                    ov  = t;
                    od  = s2 * zd;
                    odd = s2 * zdd - 2.0f * t * s2 * zd * zd;
                } else {
                    ov = zv; od = zd; odd = zdd;
                }
                if (o0 + r >= FOUT) { ov = 0.f; od = 0.f; odd = 0.f; }
                if (lowHalf) {
                    Split sv = split16(ov);
                    pA[r] = sv.hi; pB[r] = sv.lo;
                } else {
                    pA[r] = (_Float16)od;
                    pB[r] = (_Float16)odd;
                }
            }
            int r0 = (lowHalf ? 0 : 16) + s;     // first write row
            *(h4*)(smem + r0 * STR + o0)       = pA;
            *(h4*)(smem + (r0 + 8) * STR + o0) = pB;
        }
    }
    __syncthreads();
}

// ---------------- main fused kernel ----------------
__global__ __launch_bounds__(THREADS, 8) void pinn_mfma(
    const float* __restrict__ W0, const float* __restrict__ b0,
    const float* __restrict__ x,  const float* __restrict__ A,
    const float* __restrict__ bvec,
    const _Float16* __restrict__ whi, const float* __restrict__ biasP,
    float* __restrict__ out)
{
    __shared__ __align__(16) _Float16 smem[32 * STR];   // 33,280 B
    __shared__ float xs[BS];

    // Fm/Um overlay the plane space after the last MFMA layer's barrier
    float* Fm = (float*)smem;              // 8 x 104 floats
    float* Um = Fm + BS * 104;

    const int tid  = threadIdx.x;
    const int bid  = blockIdx.x;
    const int lane = tid & 63;
    const int wv   = tid >> 6;
    const _Float16* wlo = whi + SW;

    if (tid < BS) xs[tid] = x[bid * BS + tid];
    __syncthreads();

    // ---- layer 0: 1 -> 20, write padded-K (32) input planes, 8 samples ----
    if (tid < 256) {
        int s = tid >> 5;       // 0..7
        int k = tid & 31;       // 0..31
        float v0 = 0.f, v1 = 0.f, v2 = 0.f;
        if (k < 20) {
            float w  = W0[k];
            float z  = w * xs[s] + b0[k];
            float t  = fast_tanh(z);
            float s2 = 1.0f - t * t;
            v0 = t; v1 = s2 * w; v2 = -2.0f * t * s2 * w * w;
        }
        Split s0 = split16(v0);
        smem[ s       * STR + k] = s0.hi;          // vhi
        smem[( 8 + s) * STR + k] = s0.lo;          // vlo
        smem[(16 + s) * STR + k] = (_Float16)v1;   // dhi
        smem[(24 + s) * STR + k] = (_Float16)v2;   // ddh
    }
    __syncthreads();

    //          KP   MT NMT NWA FOUT
    layer_mfma< 32,  4, 1,  4,  50, true>(whi, wlo, C1, biasP + BP1, smem, lane, wv);
    layer_mfma< 64, 14, 2,  7, 200, true>(whi, wlo, C2, biasP + BP2, smem, lane, wv);
    layer_mfma<224, 32, 4,  8, 500, true>(whi, wlo, C3, biasP + BP3, smem, lane, wv);
    layer_mfma<512, 14, 2,  7, 200, true>(whi, wlo, C4, biasP + BP4, smem, lane, wv);

    // ---- layer 5: 200 -> 100 linear, epilogue -> U, Uxx, F (overlay) ----
    {
        constexpr int KT = 7;
        const int colS = lane & 15;
        const int kg   = lane >> 4;
        const bool act = (wv < 7);
        _Float16* Pv = smem;
        _Float16* Pd = smem + 16 * STR;
        f4 accV = (f4){0.f,0.f,0.f,0.f}, accD = accV;
        if (act) {
            const int boff = colS * STR + kg * 8;
            const unsigned w5off = (unsigned)(C5 + (wv * KT) * 512 + lane * 8);
#pragma unroll 2
            for (int kt = 0; kt < KT; ++kt) {
                const int kb  = kt * 32;
                const int kwb = kt * 512;
                h8 B1 = *(const h8*)(Pv + boff + kb);
                h8 B2 = *(const h8*)(Pd + boff + kb);
                h8 Ahi = *(const h8*)(whi + w5off + kwb);
                h8 Alo = *(const h8*)(wlo + w5off + kwb);
                __builtin_amdgcn_s_setprio(1);
                accV = __builtin_amdgcn_mfma_f32_16x16x32_f16(Ahi, B1, accV, 0, 0, 0);
                accV = __builtin_amdgcn_mfma_f32_16x16x32_f16(Alo, B1, accV, 0, 0, 0);
                accD = __builtin_amdgcn_mfma_f32_16x16x32_f16(Ahi, B2, accD, 0, 0, 0);
                __builtin_amdgcn_s_setprio(0);
            }
        }
        __syncthreads();   // planes dead after this point; overlay Fm/Um
        if (act) {
            int o0 = wv * 16 + kg * 4;
            f4 bi = *(const f4*)(biasP + BP5 + o0);
            int s = colS & 7;
            float xv = xs[s];
            float xm = xv * xv - 1.0f;
#pragma unroll
            for (int r = 0; r < 4; ++r) {
                float a1  = accV[r];
                float a2  = accD[r];
                float a1s = __shfl_xor(a1, 8);
                float a2s = __shfl_xor(a2, 8);
                int q = o0 + r;
                if (colS < 8 && q < Q) {
                    float gv  = a1 + a1s + bi[r];
                    float gd  = a2;
                    float gdd = a2s;
                    float U   = -1.0f + xm * gv;
                    float Uxx = 2.0f * gv + 4.0f * xv * gd + xm * gdd;
                    float Fv  = 5.0f * U * U * U - 5.0f * U - 0.0005f * Uxx;
                    Fm[s * 104 + q] = Fv;
                    Um[s * 104 + q] = U;
                }
            }
        }
        __syncthreads();
    }

    // ---- tail: U0 = U + DT*F@A^T ; U1 = U0 - DT*(F@bvec^T) (fp32 vector) ----
    {
        int qc = tid & 63;          // candidate q (and q+64)
        int ss = tid >> 6;          // sample 0..7
        float accq[2] = {0.f, 0.f};
        float cb = 0.f;
        const float* Fr = Fm + ss * 104;
#pragma unroll 5
        for (int j = 0; j < Q; j += 4) {
            f4 f4v = *(const f4*)(Fr + j);
            f4 bv4 = *(const f4*)(bvec + j);
            cb += f4v[0]*bv4[0] + f4v[1]*bv4[1] + f4v[2]*bv4[2] + f4v[3]*bv4[3];
#pragma unroll
            for (int u = 0; u < 2; ++u) {
                int q   = qc + 64 * u;
                int qcl = q < Q ? q : Q - 1;
                f4 a4 = *(const f4*)(A + qcl * Q + j);
                accq[u] += f4v[0]*a4[0] + f4v[1]*a4[1] + f4v[2]*a4[2] + f4v[3]*a4[3];
            }
        }
        int sg = bid * BS + ss;
#pragma unroll
        for (int u = 0; u < 2; ++u) {
            int q = qc + 64 * u;
            if (q < Q) {
                float U0 = Um[ss * 104 + q] + DTC * accq[u];
                float U1 = U0 - DTC * cb;
                out[sg * Q + q] = U0;
                out[NSAMP * Q + sg * Q + q] = U1;
            }
        }
    }
}

extern "C" void kernel_launch(void* const* d_in, const int* in_sizes, int n_in,
                              void* d_out, int out_size, void* d_ws, size_t ws_size,
                              hipStream_t stream) {
    const float* W0 = (const float*)d_in[0];
    const float* b0 = (const float*)d_in[1];
    const float* W1 = (const float*)d_in[2];
    const float* b1 = (const float*)d_in[3];
    const float* W2 = (const float*)d_in[4];
    const float* b2 = (const float*)d_in[5];
    const float* W3 = (const float*)d_in[6];
    const float* b3 = (const float*)d_in[7];
    const float* W4 = (const float*)d_in[8];
    const float* b4 = (const float*)d_in[9];
    const float* W5 = (const float*)d_in[10];
    const float* b5 = (const float*)d_in[11];
    const float* x  = (const float*)d_in[12];
    const float* A  = (const float*)d_in[13];
    const float* bv = (const float*)d_in[14];
    float* out = (float*)d_out;

    _Float16* whi = (_Float16*)d_ws;
    float* biasP  = (float*)((char*)d_ws + WS_BIAS_BYTE_OFF);

    prepass<<<(SW + BPTOT + 255) / 256, 256, 0, stream>>>(
        W1, b1, W2, b2, W3, b3, W4, b4, W5, b5, whi, biasP);

    pinn_mfma<<<NSAMP / BS, THREADS, 0, stream>>>(
        W0, b0, x, A, bv, whi, biasP, out);
}

// Round 4
// 579.561 us; speedup vs baseline: 1.2612x; 1.2612x over previous
//
#include <hip/hip_runtime.h>
#include <hip/hip_bf16.h>

// PINN fused forward+jvp^2 via split-fp16 MFMA.
// R14: R13's packed-column structure (BS=8, 512 thr, 33.3KB LDS, 3 MFMAs per
// (mt,kt): B1=[vhi|vlo], B2=[dhi|ddh]) with the occupancy ask corrected to
// __launch_bounds__(512, 6): gfx950's VGPR/AGPR file is UNIFIED, so R13's
// (512,8) capped VGPR+AGPR at 64 total and spilled the accumulators to
// scratch (621MB WRITE_SIZE). (512,6) gives an 85-reg unified budget: L3
// needs ~32 AGPR acc + ~40 VGPR working set = ~72. -> 24 waves/CU,
// 3 blocks/CU resident (LDS 3x33.8KB=101KB), out-of-phase barrier masking.

#define NSAMP 65536
#define Q     100
#define DTC   0.8f
#define BS    8
#define THREADS 512
#define STR   520          // LDS row stride (halves)

typedef _Float16 h8 __attribute__((ext_vector_type(8)));
typedef _Float16 h4 __attribute__((ext_vector_type(4)));
typedef float    f4 __attribute__((ext_vector_type(4)));

// ---- packed fragment-ready weight geometry (halves) ----
// per layer: MT * KT * 512 halves (frag = 64 lanes x 8 halves)
// L1: MT=4,  KT=1  ->   2048
// L2: MT=14, KT=2  ->  14336
// L3: MT=32, KT=7  -> 114688
// L4: MT=14, KT=16 -> 114688
// L5: MT=7,  KT=7  ->  25088
#define SW 270848
#define C1 0
#define C2 2048
#define C3 16384
#define C4 131072
#define C5 245760
#define BP1 0
#define BP2 64
#define BP3 288
#define BP4 800
#define BP5 1024
#define BPTOT 1136
#define WS_BIAS_BYTE_OFF (SW*2*2)

__device__ __forceinline__ float fast_tanh(float z) {
    float az = fabsf(z);
    float e  = __expf(-2.0f * az);
    float r  = __builtin_amdgcn_rcpf(1.0f + e);
    float t  = (1.0f - e) * r;
    return copysignf(t, z);
}

struct Split { _Float16 hi, lo; };
__device__ __forceinline__ Split split16(float v) {
    Split s;
    s.hi = (_Float16)v;
    s.lo = (_Float16)(v - (float)s.hi);
    return s;
}

// ---------------- pre-pass: split/pad/PACK weights + biases into d_ws ----------------
__global__ __launch_bounds__(256) void prepass(
    const float* __restrict__ W1, const float* __restrict__ b1,
    const float* __restrict__ W2, const float* __restrict__ b2,
    const float* __restrict__ W3, const float* __restrict__ b3,
    const float* __restrict__ W4, const float* __restrict__ b4,
    const float* __restrict__ W5, const float* __restrict__ b5,
    _Float16* __restrict__ whi, float* __restrict__ biasP)
{
    int idx = blockIdx.x * 256 + threadIdx.x;
    _Float16* wlo = whi + SW;
    if (idx < SW) {
        int base, KT, K, FOUT; const float* W;
        if      (idx < C2) { base=C1; KT=1;  K=20;  FOUT=50;  W=W1; }
        else if (idx < C3) { base=C2; KT=2;  K=50;  FOUT=200; W=W2; }
        else if (idx < C4) { base=C3; KT=7;  K=200; FOUT=500; W=W3; }
        else if (idx < C5) { base=C4; KT=16; K=500; FOUT=200; W=W4; }
        else               { base=C5; KT=7;  K=200; FOUT=100; W=W5; }
        int r    = idx - base;
        int frag = r >> 9;
        int f    = r & 511;
        int lane = f >> 3;
        int e    = f & 7;
        int colS = lane & 15;
        int kg   = lane >> 4;
        int mt   = frag / KT;
        int kt   = frag - mt * KT;
        int o = mt * 16 + colS;
        int k = kt * 32 + kg * 8 + e;
        float v = (o < FOUT && k < K) ? W[o * K + k] : 0.f;
        Split sp = split16(v);
        whi[idx] = sp.hi; wlo[idx] = sp.lo;
    } else if (idx < SW + BPTOT) {
        int b = idx - SW;
        const float* src; int FOUT; int o;
        if      (b < BP2)  { src=b1; FOUT=50;  o=b;        }
        else if (b < BP3)  { src=b2; FOUT=200; o=b-BP2;    }
        else if (b < BP4)  { src=b3; FOUT=500; o=b-BP3;    }
        else if (b < BP5)  { src=b4; FOUT=200; o=b-BP4;    }
        else               { src=b5; FOUT=100; o=b-BP5;    }
        biasP[b] = (o < FOUT) ? src[o] : 0.f;
    }
}

// ---------------- one MFMA layer (packed columns, 8 samples) ----------------
// LDS: 32 rows x STR halves. Rows 0-7: vhi, 8-15: vlo, 16-23: dhi, 24-31: ddh.
// B1 (v-region) lane l -> row = l&15 (covers vhi|vlo), k0 = (l>>4)*8 + kt*32.
// B2 (d-region) = same formula at smem + 16*STR.
// A-frag: PACKED: base + (mt*KT + kt)*512 + lane*8 -> coalesced 1KB load.
// C/D: col(lane&15): c<8 -> channel A of sample c, c>=8 -> channel B of c-8.
// 3 MFMAs per (mt,kt): accV += Ahi*B1 + Alo*B1 ; accD += Ahi*B2.
template<int KP, int MTILES, int NMT, int NWACT, int FOUT, bool TANH>
__device__ __forceinline__ void layer_mfma(
    const _Float16* __restrict__ whi, const _Float16* __restrict__ wlo,
    int wcoff, const float* __restrict__ biasP,
    _Float16* smem, int lane, int wv)
{
    constexpr int KT = KP / 32;
    static_assert(MTILES == NMT * NWACT, "exact tiling expected");
    const int colS = lane & 15;
    const int kg   = lane >> 4;
    const bool act = (wv < NWACT);
    _Float16* Pv = smem;
    _Float16* Pd = smem + 16 * STR;

    f4 accV[NMT], accD[NMT];

    if (act) {
#pragma unroll
        for (int i = 0; i < NMT; ++i) {
            accV[i] = (f4){0.f, 0.f, 0.f, 0.f};
            accD[i] = (f4){0.f, 0.f, 0.f, 0.f};
        }

        const int boff = colS * STR + kg * 8;

        unsigned woff[NMT];
#pragma unroll
        for (int i = 0; i < NMT; ++i)
            woff[i] = (unsigned)(wcoff + ((wv + NWACT * i) * KT) * 512 + lane * 8);

#pragma unroll 2
        for (int kt = 0; kt < KT; ++kt) {
            const int kb  = kt * 32;
            const int kwb = kt * 512;
            h8 B1 = *(const h8*)(Pv + boff + kb);
            h8 B2 = *(const h8*)(Pd + boff + kb);
            __builtin_amdgcn_s_setprio(1);
#pragma unroll
            for (int i = 0; i < NMT; ++i) {
                h8 Ahi = *(const h8*)(whi + woff[i] + kwb);
                h8 Alo = *(const h8*)(wlo + woff[i] + kwb);
                accV[i] = __builtin_amdgcn_mfma_f32_16x16x32_f16(Ahi, B1, accV[i], 0, 0, 0);
                accV[i] = __builtin_amdgcn_mfma_f32_16x16x32_f16(Alo, B1, accV[i], 0, 0, 0);
                accD[i] = __builtin_amdgcn_mfma_f32_16x16x32_f16(Ahi, B2, accD[i], 0, 0, 0);
            }
            __builtin_amdgcn_s_setprio(0);
        }
    }
    __syncthreads();   // all reads of planes complete before in-place overwrite

    if (act) {
        const bool lowHalf = (colS < 8);
        const int  s       = colS & 7;
#pragma unroll
        for (int i = 0; i < NMT; ++i) {
            int mt = wv + NWACT * i;
            int o0 = mt * 16 + kg * 4;
            f4 bi = *(const f4*)(biasP + o0);
            h4 pA, pB;   // lowHalf: (vhi, vlo) ; else: (dhi, ddh)
#pragma unroll
            for (int r = 0; r < 4; ++r) {
                float a1  = accV[i][r];
                float a2  = accD[i][r];
                float a1s = __shfl_xor(a1, 8);
                float a2s = __shfl_xor(a2, 8);
                float zv  = a1 + a1s + bi[r];        // full split product
                float zd  = lowHalf ? a2  : a2s;
                float zdd = lowHalf ? a2s : a2;
                float ov, od, odd;
                if constexpr (TANH) {
                    float t  = fast_tanh(zv);
                    float s2 = 1.0f - t * t;
                    ov  = t;
                    od  = s2 * zd;
                    odd = s2 * zdd - 2.0f * t * s2 * zd * zd;
                } else {
                    ov = zv; od = zd; odd = zdd;
                }
                if (o0 + r >= FOUT) { ov = 0.f; od = 0.f; odd = 0.f; }
                if (lowHalf) {
                    Split sv = split16(ov);
                    pA[r] = sv.hi; pB[r] = sv.lo;
                } else {
                    pA[r] = (_Float16)od;
                    pB[r] = (_Float16)odd;
                }
            }
            int r0 = (lowHalf ? 0 : 16) + s;     // first write row
            *(h4*)(smem + r0 * STR + o0)       = pA;
            *(h4*)(smem + (r0 + 8) * STR + o0) = pB;
        }
    }
    __syncthreads();
}

// ---------------- main fused kernel ----------------
__global__ __launch_bounds__(THREADS, 6) void pinn_mfma(
    const float* __restrict__ W0, const float* __restrict__ b0,
    const float* __restrict__ x,  const float* __restrict__ A,
    const float* __restrict__ bvec,
    const _Float16* __restrict__ whi, const float* __restrict__ biasP,
    float* __restrict__ out)
{
    __shared__ __align__(16) _Float16 smem[32 * STR];   // 33,280 B
    __shared__ float xs[BS];

    // Fm/Um overlay the plane space after the last MFMA layer's barrier
    float* Fm = (float*)smem;              // 8 x 104 floats
    float* Um = Fm + BS * 104;

    const int tid  = threadIdx.x;
    const int bid  = blockIdx.x;
    const int lane = tid & 63;
    const int wv   = tid >> 6;
    const _Float16* wlo = whi + SW;

    if (tid < BS) xs[tid] = x[bid * BS + tid];
    __syncthreads();

    // ---- layer 0: 1 -> 20, write padded-K (32) input planes, 8 samples ----
    if (tid < 256) {
        int s = tid >> 5;       // 0..7
        int k = tid & 31;       // 0..31
        float v0 = 0.f, v1 = 0.f, v2 = 0.f;
        if (k < 20) {
            float w  = W0[k];
            float z  = w * xs[s] + b0[k];
            float t  = fast_tanh(z);
            float s2 = 1.0f - t * t;
            v0 = t; v1 = s2 * w; v2 = -2.0f * t * s2 * w * w;
        }
        Split s0 = split16(v0);
        smem[ s       * STR + k] = s0.hi;          // vhi
        smem[( 8 + s) * STR + k] = s0.lo;          // vlo
        smem[(16 + s) * STR + k] = (_Float16)v1;   // dhi
        smem[(24 + s) * STR + k] = (_Float16)v2;   // ddh
    }
    __syncthreads();

    //          KP   MT NMT NWA FOUT
    layer_mfma< 32,  4, 1,  4,  50, true>(whi, wlo, C1, biasP + BP1, smem, lane, wv);
    layer_mfma< 64, 14, 2,  7, 200, true>(whi, wlo, C2, biasP + BP2, smem, lane, wv);
    layer_mfma<224, 32, 4,  8, 500, true>(whi, wlo, C3, biasP + BP3, smem, lane, wv);
    layer_mfma<512, 14, 2,  7, 200, true>(whi, wlo, C4, biasP + BP4, smem, lane, wv);

    // ---- layer 5: 200 -> 100 linear, epilogue -> U, Uxx, F (overlay) ----
    {
        constexpr int KT = 7;
        const int colS = lane & 15;
        const int kg   = lane >> 4;
        const bool act = (wv < 7);
        _Float16* Pv = smem;
        _Float16* Pd = smem + 16 * STR;
        f4 accV = (f4){0.f,0.f,0.f,0.f}, accD = accV;
        if (act) {
            const int boff = colS * STR + kg * 8;
            const unsigned w5off = (unsigned)(C5 + (wv * KT) * 512 + lane * 8);
#pragma unroll 2
            for (int kt = 0; kt < KT; ++kt) {
                const int kb  = kt * 32;
                const int kwb = kt * 512;
                h8 B1 = *(const h8*)(Pv + boff + kb);
                h8 B2 = *(const h8*)(Pd + boff + kb);
                h8 Ahi = *(const h8*)(whi + w5off + kwb);
                h8 Alo = *(const h8*)(wlo + w5off + kwb);
                __builtin_amdgcn_s_setprio(1);
                accV = __builtin_amdgcn_mfma_f32_16x16x32_f16(Ahi, B1, accV, 0, 0, 0);
                accV = __builtin_amdgcn_mfma_f32_16x16x32_f16(Alo, B1, accV, 0, 0, 0);
                accD = __builtin_amdgcn_mfma_f32_16x16x32_f16(Ahi, B2, accD, 0, 0, 0);
                __builtin_amdgcn_s_setprio(0);
            }
        }
        __syncthreads();   // planes dead after this point; overlay Fm/Um
        if (act) {
            int o0 = wv * 16 + kg * 4;
            f4 bi = *(const f4*)(biasP + BP5 + o0);
            int s = colS & 7;
            float xv = xs[s];
            float xm = xv * xv - 1.0f;
#pragma unroll
            for (int r = 0; r < 4; ++r) {
                float a1  = accV[r];
                float a2  = accD[r];
                float a1s = __shfl_xor(a1, 8);
                float a2s = __shfl_xor(a2, 8);
                int q = o0 + r;
                if (colS < 8 && q < Q) {
                    float gv  = a1 + a1s + bi[r];
                    float gd  = a2;
                    float gdd = a2s;
                    float U   = -1.0f + xm * gv;
                    float Uxx = 2.0f * gv + 4.0f * xv * gd + xm * gdd;
                    float Fv  = 5.0f * U * U * U - 5.0f * U - 0.0005f * Uxx;
                    Fm[s * 104 + q] = Fv;
                    Um[s * 104 + q] = U;
                }
            }
        }
        __syncthreads();
    }

    // ---- tail: U0 = U + DT*F@A^T ; U1 = U0 - DT*(F@bvec^T) (fp32 vector) ----
    {
        int qc = tid & 63;          // candidate q (and q+64)
        int ss = tid >> 6;          // sample 0..7
        float accq[2] = {0.f, 0.f};
        float cb = 0.f;
        const float* Fr = Fm + ss * 104;
#pragma unroll 5
        for (int j = 0; j < Q; j += 4) {
            f4 f4v = *(const f4*)(Fr + j);
            f4 bv4 = *(const f4*)(bvec + j);
            cb += f4v[0]*bv4[0] + f4v[1]*bv4[1] + f4v[2]*bv4[2] + f4v[3]*bv4[3];
#pragma unroll
            for (int u = 0; u < 2; ++u) {
                int q   = qc + 64 * u;
                int qcl = q < Q ? q : Q - 1;
                f4 a4 = *(const f4*)(A + qcl * Q + j);
                accq[u] += f4v[0]*a4[0] + f4v[1]*a4[1] + f4v[2]*a4[2] + f4v[3]*a4[3];
            }
        }
        int sg = bid * BS + ss;
#pragma unroll
        for (int u = 0; u < 2; ++u) {
            int q = qc + 64 * u;
            if (q < Q) {
                float U0 = Um[ss * 104 + q] + DTC * accq[u];
                float U1 = U0 - DTC * cb;
                out[sg * Q + q] = U0;
                out[NSAMP * Q + sg * Q + q] = U1;
            }
        }
    }
}

extern "C" void kernel_launch(void* const* d_in, const int* in_sizes, int n_in,
                              void* d_out, int out_size, void* d_ws, size_t ws_size,
                              hipStream_t stream) {
    const float* W0 = (const float*)d_in[0];
    const float* b0 = (const float*)d_in[1];
    const float* W1 = (const float*)d_in[2];
    const float* b1 = (const float*)d_in[3];
    const float* W2 = (const float*)d_in[4];
    const float* b2 = (const float*)d_in[5];
    const float* W3 = (const float*)d_in[6];
    const float* b3 = (const float*)d_in[7];
    const float* W4 = (const float*)d_in[8];
    const float* b4 = (const float*)d_in[9];
    const float* W5 = (const float*)d_in[10];
    const float* b5 = (const float*)d_in[11];
    const float* x  = (const float*)d_in[12];
    const float* A  = (const float*)d_in[13];
    const float* bv = (const float*)d_in[14];
    float* out = (float*)d_out;

    _Float16* whi = (_Float16*)d_ws;
    float* biasP  = (float*)((char*)d_ws + WS_BIAS_BYTE_OFF);

    prepass<<<(SW + BPTOT + 255) / 256, 256, 0, stream>>>(
        W1, b1, W2, b2, W3, b3, W4, b4, W5, b5, whi, biasP);

    pinn_mfma<<<NSAMP / BS, THREADS, 0, stream>>>(
        W0, b0, x, A, bv, whi, biasP, out);
}

// Round 5
// 458.878 us; speedup vs baseline: 1.5929x; 1.2630x over previous
//
#include <hip/hip_runtime.h>
#include <hip/hip_bf16.h>

// PINN fused forward+jvp^2 via split-fp16 MFMA.
// R15: BS=16 (best amortization, R12) with 1024-thread blocks and 2 blocks/CU
// -> 32 waves/CU (2x R12's TLP). Designed for the 64-reg unified VGPR+AGPR
// cap at 8 waves/SIMD (R13's spill lesson): NMT=1 for L2/L4 (acc 16 regs
// w/ vb-split), NMT=2 for L3 (acc 24, no split), NO software A-staging
// (TLP replaces it), #pragma unroll 1 on kt loops to keep live ranges
// one-iteration. NWACT=14-16 so the extra waves all do real work.
// LDS 66.6KB/block, 2 resident = 134KB. Tail/layer0 re-laid for 1024 thr.

#define NSAMP 65536
#define Q     100
#define DTC   0.8f
#define BS    16
#define THREADS 1024
#define STR   520          // LDS plane stride (halves)

typedef _Float16 h8 __attribute__((ext_vector_type(8)));
typedef _Float16 h4 __attribute__((ext_vector_type(4)));
typedef float    f4 __attribute__((ext_vector_type(4)));

// ---- packed fragment-ready weight geometry (halves) ----
// per layer: MT * KT * 512 halves (frag = 64 lanes x 8 halves)
// L1: MT=4,  KT=1  ->   2048
// L2: MT=14, KT=2  ->  14336
// L3: MT=32, KT=7  -> 114688
// L4: MT=14, KT=16 -> 114688
// L5: MT=7,  KT=7  ->  25088
#define SW 270848
#define C1 0
#define C2 2048
#define C3 16384
#define C4 131072
#define C5 245760
#define BP1 0
#define BP2 64
#define BP3 288
#define BP4 800
#define BP5 1024
#define BPTOT 1136
#define WS_BIAS_BYTE_OFF (SW*2*2)

__device__ __forceinline__ float fast_tanh(float z) {
    float az = fabsf(z);
    float e  = __expf(-2.0f * az);
    float r  = __builtin_amdgcn_rcpf(1.0f + e);
    float t  = (1.0f - e) * r;
    return copysignf(t, z);
}

struct Split { _Float16 hi, lo; };
__device__ __forceinline__ Split split16(float v) {
    Split s;
    s.hi = (_Float16)v;
    s.lo = (_Float16)(v - (float)s.hi);
    return s;
}

// ---------------- pre-pass: split/pad/PACK weights + biases into d_ws ----------------
__global__ __launch_bounds__(256) void prepass(
    const float* __restrict__ W1, const float* __restrict__ b1,
    const float* __restrict__ W2, const float* __restrict__ b2,
    const float* __restrict__ W3, const float* __restrict__ b3,
    const float* __restrict__ W4, const float* __restrict__ b4,
    const float* __restrict__ W5, const float* __restrict__ b5,
    _Float16* __restrict__ whi, float* __restrict__ biasP)
{
    int idx = blockIdx.x * 256 + threadIdx.x;
    _Float16* wlo = whi + SW;
    if (idx < SW) {
        int base, KT, K, FOUT; const float* W;
        if      (idx < C2) { base=C1; KT=1;  K=20;  FOUT=50;  W=W1; }
        else if (idx < C3) { base=C2; KT=2;  K=50;  FOUT=200; W=W2; }
        else if (idx < C4) { base=C3; KT=7;  K=200; FOUT=500; W=W3; }
        else if (idx < C5) { base=C4; KT=16; K=500; FOUT=200; W=W4; }
        else               { base=C5; KT=7;  K=200; FOUT=100; W=W5; }
        int r    = idx - base;
        int frag = r >> 9;
        int f    = r & 511;
        int lane = f >> 3;
        int e    = f & 7;
        int colS = lane & 15;
        int kg   = lane >> 4;
        int mt   = frag / KT;
        int kt   = frag - mt * KT;
        int o = mt * 16 + colS;
        int k = kt * 32 + kg * 8 + e;
        float v = (o < FOUT && k < K) ? W[o * K + k] : 0.f;
        Split sp = split16(v);
        whi[idx] = sp.hi; wlo[idx] = sp.lo;
    } else if (idx < SW + BPTOT) {
        int b = idx - SW;
        const float* src; int FOUT; int o;
        if      (b < BP2)  { src=b1; FOUT=50;  o=b;        }
        else if (b < BP3)  { src=b2; FOUT=200; o=b-BP2;    }
        else if (b < BP4)  { src=b3; FOUT=500; o=b-BP3;    }
        else if (b < BP5)  { src=b4; FOUT=200; o=b-BP4;    }
        else               { src=b5; FOUT=100; o=b-BP5;    }
        biasP[b] = (o < FOUT) ? src[o] : 0.f;
    }
}

// ---------------- one MFMA layer ----------------
// Planes (LDS, stride STR halves): vhi, vlo (split v-state), dhi, ddh (fp16 d/dd).
// B-frag: lane l -> col = l&15 (sample), k0 = (l>>4)*8 + kt*32.
// A-frag: PACKED: base + (mt*KT + kt)*512 + lane*8  -> coalesced 1KB load.
// C/D: col(lane&15)=sample, row((lane>>4)*4+reg)=output neuron.
// VSPLIT (NMT==1): v accumulated in two chains (va: Ahi*Bvh; vb: Ahi*Bvl+Alo*Bvh).
template<int KP, int MTILES, int NMT, int NWACT, int FOUT, bool TANH>
__device__ __forceinline__ void layer_mfma(
    const _Float16* __restrict__ whi, const _Float16* __restrict__ wlo,
    int wcoff, const float* __restrict__ biasP,
    _Float16* vhi, _Float16* vlo, _Float16* dhi, _Float16* ddh,
    int lane, int wv)
{
    constexpr int KT = KP / 32;
    constexpr bool VSPLIT = (NMT == 1);
    static_assert(MTILES == NMT * NWACT, "exact tiling expected");
    const int colS = lane & 15;
    const int kg   = lane >> 4;
    const bool act = (wv < NWACT);

    f4 accva[NMT], accvb[VSPLIT ? NMT : 1], accd[NMT], accdd[NMT];

    if (act) {
#pragma unroll
        for (int i = 0; i < NMT; ++i) {
            accva[i] = (f4){0.f, 0.f, 0.f, 0.f};
            accd[i]  = (f4){0.f, 0.f, 0.f, 0.f};
            accdd[i] = (f4){0.f, 0.f, 0.f, 0.f};
        }
        if constexpr (VSPLIT) {
#pragma unroll
            for (int i = 0; i < NMT; ++i)
                accvb[i] = (f4){0.f, 0.f, 0.f, 0.f};
        }

        const int boff = colS * STR + kg * 8;
        const unsigned wbase = (unsigned)(wcoff + (wv * KT) * 512 + lane * 8);

#pragma unroll 1
        for (int kt = 0; kt < KT; ++kt) {
            const int kb  = kt * 32;
            const int kwb = kt * 512;
            h8 Bvh = *(const h8*)(vhi + boff + kb);
            h8 Bvl = *(const h8*)(vlo + boff + kb);
            h8 Bdh = *(const h8*)(dhi + boff + kb);
            h8 Bdd = *(const h8*)(ddh + boff + kb);
            __builtin_amdgcn_s_setprio(1);
#pragma unroll
            for (int i = 0; i < NMT; ++i) {
                const unsigned wo = wbase + (unsigned)(i * (NWACT * KT * 512)) + kwb;
                h8 Ahi = *(const h8*)(whi + wo);
                h8 Alo = *(const h8*)(wlo + wo);
                accva[i] = __builtin_amdgcn_mfma_f32_16x16x32_f16(Ahi, Bvh, accva[i], 0, 0, 0);
                if constexpr (VSPLIT) {
                    accvb[i] = __builtin_amdgcn_mfma_f32_16x16x32_f16(Ahi, Bvl, accvb[i], 0, 0, 0);
                    accvb[i] = __builtin_amdgcn_mfma_f32_16x16x32_f16(Alo, Bvh, accvb[i], 0, 0, 0);
                } else {
                    accva[i] = __builtin_amdgcn_mfma_f32_16x16x32_f16(Ahi, Bvl, accva[i], 0, 0, 0);
                    accva[i] = __builtin_amdgcn_mfma_f32_16x16x32_f16(Alo, Bvh, accva[i], 0, 0, 0);
                }
                accd[i]  = __builtin_amdgcn_mfma_f32_16x16x32_f16(Ahi, Bdh, accd[i],  0, 0, 0);
                accdd[i] = __builtin_amdgcn_mfma_f32_16x16x32_f16(Ahi, Bdd, accdd[i], 0, 0, 0);
            }
            __builtin_amdgcn_s_setprio(0);
        }
    }
    __syncthreads();   // all reads of planes complete before in-place overwrite

    if (act) {
#pragma unroll
        for (int i = 0; i < NMT; ++i) {
            int mt = wv + NWACT * i;
            int o0 = mt * 16 + kg * 4;
            f4 bi = *(const f4*)(biasP + o0);
            h4 pvh, pvl, pdh, pdd;
#pragma unroll
            for (int r = 0; r < 4; ++r) {
                float zv;
                if constexpr (VSPLIT) zv = accva[i][r] + accvb[i][r] + bi[r];
                else                  zv = accva[i][r] + bi[r];
                float zd  = accd[i][r];
                float zdd = accdd[i][r];
                float ov, od, odd;
                if constexpr (TANH) {
                    float t  = fast_tanh(zv);
                    float s2 = 1.0f - t * t;
                    ov  = t;
                    od  = s2 * zd;
                    odd = s2 * zdd - 2.0f * t * s2 * zd * zd;
                } else {
                    ov = zv; od = zd; odd = zdd;
                }
                if (o0 + r >= FOUT) { ov = 0.f; od = 0.f; odd = 0.f; }
                Split sv = split16(ov);
                pvh[r] = sv.hi; pvl[r] = sv.lo;
                pdh[r] = (_Float16)od;
                pdd[r] = (_Float16)odd;
            }
            int off = colS * STR + o0;
            *(h4*)(vhi + off) = pvh;
            *(h4*)(vlo + off) = pvl;
            *(h4*)(dhi + off) = pdh;
            *(h4*)(ddh + off) = pdd;
        }
    }
    __syncthreads();
}

// ---------------- main fused kernel ----------------
__global__ __launch_bounds__(THREADS, 8) void pinn_mfma(
    const float* __restrict__ W0, const float* __restrict__ b0,
    const float* __restrict__ x,  const float* __restrict__ A,
    const float* __restrict__ bvec,
    const _Float16* __restrict__ whi, const float* __restrict__ biasP,
    float* __restrict__ out)
{
    __shared__ __align__(16) _Float16 smem[4 * BS * STR];   // 66,560 B
    __shared__ float xs[BS];

    _Float16* vhi = smem + 0 * BS * STR;
    _Float16* vlo = smem + 1 * BS * STR;
    _Float16* dhi = smem + 2 * BS * STR;
    _Float16* ddh = smem + 3 * BS * STR;
    // Fm/Um overlay the plane space after the last MFMA layer's barrier
    float* Fm = (float*)smem;              // 16 x 104 floats
    float* Um = Fm + BS * 104;

    const int tid  = threadIdx.x;
    const int bid  = blockIdx.x;
    const int lane = tid & 63;
    const int wv   = tid >> 6;
    const _Float16* wlo = whi + SW;

    if (tid < BS) xs[tid] = x[bid * BS + tid];
    __syncthreads();

    // ---- layer 0: 1 -> 20, write padded-K (32) input planes ----
    if (tid < 512) {
        int s = tid >> 5;       // 0..15
        int k = tid & 31;       // 0..31
        float v0 = 0.f, v1 = 0.f, v2 = 0.f;
        if (k < 20) {
            float w  = W0[k];
            float z  = w * xs[s] + b0[k];
            float t  = fast_tanh(z);
            float s2 = 1.0f - t * t;
            v0 = t; v1 = s2 * w; v2 = -2.0f * t * s2 * w * w;
        }
        Split s0 = split16(v0);
        int off = s * STR + k;
        vhi[off] = s0.hi;           vlo[off] = s0.lo;
        dhi[off] = (_Float16)v1;    ddh[off] = (_Float16)v2;
    }
    __syncthreads();

    //          KP   MT NMT NWA  FOUT
    layer_mfma< 32,  4, 1,  4,   50, true>(whi, wlo, C1, biasP + BP1, vhi, vlo, dhi, ddh, lane, wv);
    layer_mfma< 64, 14, 1, 14,  200, true>(whi, wlo, C2, biasP + BP2, vhi, vlo, dhi, ddh, lane, wv);
    layer_mfma<224, 32, 2, 16,  500, true>(whi, wlo, C3, biasP + BP3, vhi, vlo, dhi, ddh, lane, wv);
    layer_mfma<512, 14, 1, 14,  200, true>(whi, wlo, C4, biasP + BP4, vhi, vlo, dhi, ddh, lane, wv);

    // ---- layer 5: 200 -> 100 linear, epilogue -> U, Uxx, F (overlay) ----
    {
        constexpr int KT = 7;
        const int colS = lane & 15;
        const int kg   = lane >> 4;
        const bool act = (wv < 7);
        f4 ava = (f4){0.f,0.f,0.f,0.f}, avb = ava, ad = ava, add = ava;
        if (act) {
            const int boff = colS * STR + kg * 8;
            const unsigned w5off = (unsigned)(C5 + (wv * KT) * 512 + lane * 8);
#pragma unroll 1
            for (int kt = 0; kt < KT; ++kt) {
                const int kb  = kt * 32;
                const int kwb = kt * 512;
                h8 Bvh = *(const h8*)(vhi + boff + kb);
                h8 Bvl = *(const h8*)(vlo + boff + kb);
                h8 Bdh = *(const h8*)(dhi + boff + kb);
                h8 Bdd = *(const h8*)(ddh + boff + kb);
                h8 Ah  = *(const h8*)(whi + w5off + kwb);
                h8 Al  = *(const h8*)(wlo + w5off + kwb);
                __builtin_amdgcn_s_setprio(1);
                ava = __builtin_amdgcn_mfma_f32_16x16x32_f16(Ah, Bvh, ava, 0, 0, 0);
                avb = __builtin_amdgcn_mfma_f32_16x16x32_f16(Ah, Bvl, avb, 0, 0, 0);
                avb = __builtin_amdgcn_mfma_f32_16x16x32_f16(Al, Bvh, avb, 0, 0, 0);
                ad  = __builtin_amdgcn_mfma_f32_16x16x32_f16(Ah, Bdh, ad,  0, 0, 0);
                add = __builtin_amdgcn_mfma_f32_16x16x32_f16(Ah, Bdd, add, 0, 0, 0);
                __builtin_amdgcn_s_setprio(0);
            }
        }
        __syncthreads();   // planes dead after this point; overlay Fm/Um
        if (act) {
            int o0 = wv * 16 + kg * 4;
            f4 bi = *(const f4*)(biasP + BP5 + o0);
            float xv = xs[colS];
            float xm = xv * xv - 1.0f;
#pragma unroll
            for (int r = 0; r < 4; ++r) {
                int q = o0 + r;
                if (q < Q) {
                    float gv  = ava[r] + avb[r] + bi[r];
                    float gd  = ad[r];
                    float gdd = add[r];
                    float U   = -1.0f + xm * gv;
                    float Uxx = 2.0f * gv + 4.0f * xv * gd + xm * gdd;
                    float Fv  = 5.0f * U * U * U - 5.0f * U - 0.0005f * Uxx;
                    Fm[colS * 104 + q] = Fv;
                    Um[colS * 104 + q] = U;
                }
            }
        }
        __syncthreads();
    }

    // ---- tail: U0 = U + DT*F@A^T ; U1 = U0 - DT*(F@bvec^T) (fp32 vector) ----
    // 16 waves: wave = sample, lane = q (and q+64).
    {
        int qc = tid & 63;          // candidate q (and q+64)
        int ss = tid >> 6;          // sample 0..15
        float accq[2] = {0.f, 0.f};
        float cb = 0.f;
        const float* Fr = Fm + ss * 104;
#pragma unroll 5
        for (int j = 0; j < Q; j += 4) {
            f4 f4v = *(const f4*)(Fr + j);
            f4 bv4 = *(const f4*)(bvec + j);
            cb += f4v[0]*bv4[0] + f4v[1]*bv4[1] + f4v[2]*bv4[2] + f4v[3]*bv4[3];
#pragma unroll
            for (int u = 0; u < 2; ++u) {
                int q   = qc + 64 * u;
                int qcl = q < Q ? q : Q - 1;
                f4 a4 = *(const f4*)(A + qcl * Q + j);
                accq[u] += f4v[0]*a4[0] + f4v[1]*a4[1] + f4v[2]*a4[2] + f4v[3]*a4[3];
            }
        }
        int sg = bid * BS + ss;
#pragma unroll
        for (int u = 0; u < 2; ++u) {
            int q = qc + 64 * u;
            if (q < Q) {
                float U0 = Um[ss * 104 + q] + DTC * accq[u];
                float U1 = U0 - DTC * cb;
                out[sg * Q + q] = U0;
                out[NSAMP * Q + sg * Q + q] = U1;
            }
        }
    }
}

extern "C" void kernel_launch(void* const* d_in, const int* in_sizes, int n_in,
                              void* d_out, int out_size, void* d_ws, size_t ws_size,
                              hipStream_t stream) {
    const float* W0 = (const float*)d_in[0];
    const float* b0 = (const float*)d_in[1];
    const float* W1 = (const float*)d_in[2];
    const float* b1 = (const float*)d_in[3];
    const float* W2 = (const float*)d_in[4];
    const float* b2 = (const float*)d_in[5];
    const float* W3 = (const float*)d_in[6];
    const float* b3 = (const float*)d_in[7];
    const float* W4 = (const float*)d_in[8];
    const float* b4 = (const float*)d_in[9];
    const float* W5 = (const float*)d_in[10];
    const float* b5 = (const float*)d_in[11];
    const float* x  = (const float*)d_in[12];
    const float* A  = (const float*)d_in[13];
    const float* bv = (const float*)d_in[14];
    float* out = (float*)d_out;

    _Float16* whi = (_Float16*)d_ws;
    float* biasP  = (float*)((char*)d_ws + WS_BIAS_BYTE_OFF);

    prepass<<<(SW + BPTOT + 255) / 256, 256, 0, stream>>>(
        W1, b1, W2, b2, W3, b3, W4, b4, W5, b5, whi, biasP);

    pinn_mfma<<<NSAMP / BS, THREADS, 0, stream>>>(
        W0, b0, x, A, bv, whi, biasP, out);
}